// Round 4
// baseline (627.870 us; speedup 1.0000x reference)
//
#include <hip/hip_runtime.h>
#include <hip/hip_bf16.h>
#include <math.h>

// ---------------------------------------------------------------------------
// GAT edge classifier. Pipeline per call:
//   CSR build (memset, count, 1-block scan, scatter)
//   emb GEMM -> 3x [ GEMM(+el/er epilogue) -> edge_prep -> aggregate ]
//   (last aggregate fuses the decomposed edge-scorer partials) -> score_out
// ---------------------------------------------------------------------------

constexpr float SLOPE = 0.2f;

// ---------- GEMM: Y = X[N,128] @ W[128,M] (+bias) [+ el/er epilogue] -------
template<int M>
__global__ __launch_bounds__(512)
void gemm_k128(const float* __restrict__ X, const float* __restrict__ W,
               const float* __restrict__ bias,
               const float* __restrict__ al, const float* __restrict__ ar,
               float* __restrict__ Y, float* __restrict__ el,
               float* __restrict__ er, int N) {
  constexpr int K = 128;
  constexpr int BM = 64;
  constexpr int CPT = M / 32;              // 4 (M=128) or 2 (M=64)
  constexpr int H = M / 64;
  __shared__ __align__(16) float Xs[BM][K];
  __shared__ __align__(16) float Wsm[K][M];

  const int tid = threadIdx.x;
  const int row0 = blockIdx.x * BM;

  #pragma unroll
  for (int j = 0; j < (BM * K) / (512 * 4); ++j) {
    int lin = tid + j * 512;
    int r = lin >> 5;
    int c4 = lin & 31;
    int gr = row0 + r;
    float4 v = make_float4(0.f, 0.f, 0.f, 0.f);
    if (gr < N) v = reinterpret_cast<const float4*>(X + (size_t)gr * K)[c4];
    reinterpret_cast<float4*>(&Xs[r][0])[c4] = v;
  }
  #pragma unroll
  for (int j = 0; j < (K * M) / (512 * 4); ++j) {
    int lin = tid + j * 512;
    reinterpret_cast<float4*>(&Wsm[0][0])[lin] =
        reinterpret_cast<const float4*>(W)[lin];
  }
  __syncthreads();

  const int tr = tid >> 5;                 // 16 row-groups of 4 rows
  const int tc = tid & 31;                 // 32 col-groups of CPT cols

  float acc[4][CPT];
  #pragma unroll
  for (int i = 0; i < 4; ++i)
    #pragma unroll
    for (int c = 0; c < CPT; ++c) acc[i][c] = 0.f;

  // k4-blocked: per 4 k-steps, 4 broadcast b128 (Xs) + 4 b128/b64 (Ws),
  // then 64/32 fmacs
  #pragma unroll 2
  for (int k4 = 0; k4 < K / 4; ++k4) {
    float4 xv[4];
    #pragma unroll
    for (int i = 0; i < 4; ++i)
      xv[i] = *reinterpret_cast<const float4*>(&Xs[tr * 4 + i][k4 * 4]);
    if constexpr (CPT == 4) {
      float4 wv[4];
      #pragma unroll
      for (int kk = 0; kk < 4; ++kk)
        wv[kk] = *reinterpret_cast<const float4*>(&Wsm[k4 * 4 + kk][tc * 4]);
      #pragma unroll
      for (int i = 0; i < 4; ++i) {
        const float* xp = reinterpret_cast<const float*>(&xv[i]);
        #pragma unroll
        for (int kk = 0; kk < 4; ++kk) {
          acc[i][0] += xp[kk] * wv[kk].x;
          acc[i][1] += xp[kk] * wv[kk].y;
          acc[i][2] += xp[kk] * wv[kk].z;
          acc[i][3] += xp[kk] * wv[kk].w;
        }
      }
    } else {
      float2 wv[4];
      #pragma unroll
      for (int kk = 0; kk < 4; ++kk)
        wv[kk] = *reinterpret_cast<const float2*>(&Wsm[k4 * 4 + kk][tc * 2]);
      #pragma unroll
      for (int i = 0; i < 4; ++i) {
        const float* xp = reinterpret_cast<const float*>(&xv[i]);
        #pragma unroll
        for (int kk = 0; kk < 4; ++kk) {
          acc[i][0] += xp[kk] * wv[kk].x;
          acc[i][1] += xp[kk] * wv[kk].y;
        }
      }
    }
  }

  float bv[CPT];
  #pragma unroll
  for (int c = 0; c < CPT; ++c) bv[c] = bias ? bias[tc * CPT + c] : 0.f;

  #pragma unroll
  for (int i = 0; i < 4; ++i) {
    int gr = row0 + tr * 4 + i;
    if (gr < N) {
      if constexpr (CPT == 4) {
        float4 o = make_float4(acc[i][0] + bv[0], acc[i][1] + bv[1],
                               acc[i][2] + bv[2], acc[i][3] + bv[3]);
        *reinterpret_cast<float4*>(&Y[(size_t)gr * M + tc * 4]) = o;
      } else {
        float2 o = make_float2(acc[i][0] + bv[0], acc[i][1] + bv[1]);
        *reinterpret_cast<float2*>(&Y[(size_t)gr * M + tc * 2]) = o;
      }
    }
  }

  // ---- fused attention-coefficient epilogue: el/er = feat . al/ar ----
  if (al != nullptr) {
    int head, colbase;
    if constexpr (CPT == 4) { head = tc >> 4; colbase = tc * 4 - head * 64; }
    else                    { head = 0;       colbase = tc * 2; }
    float av[CPT], rv[CPT];
    #pragma unroll
    for (int c = 0; c < CPT; ++c) {
      av[c] = al[head * 64 + colbase + c];
      rv[c] = ar[head * 64 + colbase + c];
    }
    #pragma unroll
    for (int i = 0; i < 4; ++i) {
      float pl = 0.f, pr = 0.f;
      #pragma unroll
      for (int c = 0; c < CPT; ++c) {
        pl += acc[i][c] * av[c];
        pr += acc[i][c] * rv[c];
      }
      if constexpr (CPT == 4) {
        #pragma unroll
        for (int off = 1; off < 16; off <<= 1) {
          pl += __shfl_xor(pl, off);
          pr += __shfl_xor(pr, off);
        }
        if ((tc & 15) == 0) {
          int gr = row0 + tr * 4 + i;
          if (gr < N) { el[gr * H + head] = pl; er[gr * H + head] = pr; }
        }
      } else {
        #pragma unroll
        for (int off = 1; off < 32; off <<= 1) {
          pl += __shfl_xor(pl, off);
          pr += __shfl_xor(pr, off);
        }
        if (tc == 0) {
          int gr = row0 + tr * 4 + i;
          if (gr < N) { el[gr] = pl; er[gr] = pr; }
        }
      }
    }
  }
}

// ------------------------------ CSR build ----------------------------------
__global__ void count_dst(const int* __restrict__ dst, int* __restrict__ cnt,
                          int E) {
  int i = blockIdx.x * blockDim.x + threadIdx.x;
  if (i < E) atomicAdd(&cnt[dst[i]], 1);
}

// single-block scan: rp = exclusive prefix of cnt, cur = copy, rp[n] = total
__global__ __launch_bounds__(1024)
void scan_all(const int* __restrict__ cnt, int* __restrict__ rp,
              int* __restrict__ cur, int n) {
  __shared__ int sm[1024];
  int tid = threadIdx.x;
  int L = (n + 1023) >> 10;
  int b = tid * L;
  int s = 0;
  for (int j = 0; j < L; ++j) {
    int idx = b + j;
    if (idx < n) s += cnt[idx];
  }
  sm[tid] = s;
  __syncthreads();
  for (int off = 1; off < 1024; off <<= 1) {
    int a = (tid >= off) ? sm[tid - off] : 0;
    __syncthreads();
    sm[tid] += a;
    __syncthreads();
  }
  int base = sm[tid] - s;                  // exclusive prefix for chunk start
  for (int j = 0; j < L; ++j) {
    int idx = b + j;
    if (idx < n) {
      rp[idx] = base;
      cur[idx] = base;
      base += cnt[idx];
    }
  }
  if (tid == 1023) rp[n] = sm[1023];
}

__global__ void scatter_edges(const int* __restrict__ src,
                              const int* __restrict__ dst,
                              int* __restrict__ cur,
                              int* __restrict__ s_csr,
                              int* __restrict__ d_csr, int E) {
  int i = blockIdx.x * blockDim.x + threadIdx.x;
  if (i < E) {
    int d = dst[i];
    int p = atomicAdd(&cur[d], 1);
    s_csr[p] = src[i];
    d_csr[p] = d;
  }
}

// ---- per-edge (CSR order) records: edat[h*E + p] = (exp(leaky), src) ------
template<int H>
__global__ void edge_prep(const int* __restrict__ s_csr,
                          const int* __restrict__ d_csr,
                          const float* __restrict__ el,
                          const float* __restrict__ er,
                          float2* __restrict__ edat, int E) {
  int i = blockIdx.x * blockDim.x + threadIdx.x;
  if (i >= E) return;
  int s = s_csr[i];
  int d = d_csr[i];
  float sb = __int_as_float(s);
  if constexpr (H == 2) {
    float2 le = reinterpret_cast<const float2*>(el)[s];
    float2 re = reinterpret_cast<const float2*>(er)[d];
    float e0 = le.x + re.x;
    float e1 = le.y + re.y;
    e0 = e0 > 0.f ? e0 : SLOPE * e0;
    e1 = e1 > 0.f ? e1 : SLOPE * e1;
    edat[i] = make_float2(__expf(e0), sb);
    edat[(size_t)E + i] = make_float2(__expf(e1), sb);
  } else {
    float ev = el[s] + er[d];
    ev = ev > 0.f ? ev : SLOPE * ev;
    edat[i] = make_float2(__expf(ev), sb);
  }
}

// ---------------- fused edge-softmax aggregation + bias + elu ---------------
// 16-lane group per (node,head): lane sl = float4 slot. No shuffles in the
// main path; each lane owns its final output float4. 8-edge unroll for MLP.
// SCORE: fuse the decomposed edge-scorer partials on the last layer.
template<int H, bool SCORE>
__global__ __launch_bounds__(256)
void gat_aggregate(const float* __restrict__ feat,
                   const float2* __restrict__ edat,
                   const float* __restrict__ bias,
                   const int* __restrict__ row_ptr,
                   float* __restrict__ hout,
                   const float* __restrict__ Wsc,
                   float* __restrict__ ps, float* __restrict__ pd,
                   int N, int E) {
  int tid = threadIdx.x;
  int pid = blockIdx.x * 16 + (tid >> 4);  // (node,head) pair id
  int sl = tid & 15;
  const int NH = N * H;
  bool live = pid < NH;
  int pc = live ? pid : 0;
  int node, head;
  if constexpr (H == 2) { node = pc >> 1; head = pc & 1; }
  else                  { node = pc;      head = 0; }
  int beg = live ? row_ptr[node] : 0;
  int end = live ? row_ptr[node + 1] : 0;

  const float4* feat4 = reinterpret_cast<const float4*>(feat);
  const int rowoff = head * 16 + sl;
  const float2* edath = edat + (size_t)head * E;

  float4 acc = make_float4(0.f, 0.f, 0.f, 0.f);
  float den = 0.f;

  for (int p = beg; p < end; p += 8) {
    #pragma unroll
    for (int j = 0; j < 8; ++j) {
      int q = p + j;
      int qc = q < end ? q : end - 1;
      float2 ed = edath[qc];
      float ex = q < end ? ed.x : 0.f;
      int s = __float_as_int(ed.y);
      float4 v = feat4[(size_t)s * (H * 16) + rowoff];
      den += ex;
      acc.x += ex * v.x;
      acc.y += ex * v.y;
      acc.z += ex * v.z;
      acc.w += ex * v.w;
    }
  }

  if (live) {
    float inv = 1.f / (den > 0.f ? den : 1.f);
    float4 bv = reinterpret_cast<const float4*>(bias)[head * 16 + sl];
    float4 r;
    r.x = acc.x * inv + bv.x;
    r.y = acc.y * inv + bv.y;
    r.z = acc.z * inv + bv.z;
    r.w = acc.w * inv + bv.w;
    r.x = r.x > 0.f ? r.x : expm1f(r.x);
    r.y = r.y > 0.f ? r.y : expm1f(r.y);
    r.z = r.z > 0.f ? r.z : expm1f(r.z);
    r.w = r.w > 0.f ? r.w : expm1f(r.w);
    reinterpret_cast<float4*>(hout)[(size_t)pid * 16 + sl] = r;

    if constexpr (SCORE) {
      // lane sl holds h3[node][4sl..4sl+3] in r; Wsc is [128][2] row-major
      float s0 = r.x * Wsc[(4 * sl + 0) * 2] + r.y * Wsc[(4 * sl + 1) * 2] +
                 r.z * Wsc[(4 * sl + 2) * 2] + r.w * Wsc[(4 * sl + 3) * 2];
      float s1 = r.x * Wsc[(4 * sl + 0) * 2 + 1] + r.y * Wsc[(4 * sl + 1) * 2 + 1] +
                 r.z * Wsc[(4 * sl + 2) * 2 + 1] + r.w * Wsc[(4 * sl + 3) * 2 + 1];
      float d0 = r.x * Wsc[(64 + 4 * sl + 0) * 2] + r.y * Wsc[(64 + 4 * sl + 1) * 2] +
                 r.z * Wsc[(64 + 4 * sl + 2) * 2] + r.w * Wsc[(64 + 4 * sl + 3) * 2];
      float d1 = r.x * Wsc[(64 + 4 * sl + 0) * 2 + 1] + r.y * Wsc[(64 + 4 * sl + 1) * 2 + 1] +
                 r.z * Wsc[(64 + 4 * sl + 2) * 2 + 1] + r.w * Wsc[(64 + 4 * sl + 3) * 2 + 1];
      #pragma unroll
      for (int off = 1; off < 16; off <<= 1) {   // stays inside 16-lane group
        s0 += __shfl_xor(s0, off);
        s1 += __shfl_xor(s1, off);
        d0 += __shfl_xor(d0, off);
        d1 += __shfl_xor(d1, off);
      }
      if (sl == 0) {
        ps[node * 2 + 0] = s0;
        ps[node * 2 + 1] = s1;
        pd[node * 2 + 0] = d0;
        pd[node * 2 + 1] = d1;
      }
    }
  }
}

// ----------------------- edge scorer output --------------------------------
__global__ void score_out(const int* __restrict__ src,
                          const int* __restrict__ dst,
                          const float* __restrict__ ps,
                          const float* __restrict__ pd,
                          const float* __restrict__ bs,
                          float* __restrict__ out, int E) {
  int i = blockIdx.x * blockDim.x + threadIdx.x;
  if (i < E) {
    int s = src[i], d = dst[i];
    float2 a = *reinterpret_cast<const float2*>(ps + (size_t)s * 2);
    float2 b = *reinterpret_cast<const float2*>(pd + (size_t)d * 2);
    float2 o;
    o.x = a.x + b.x + bs[0];
    o.y = a.y + b.y + bs[1];
    *reinterpret_cast<float2*>(out + (size_t)i * 2) = o;
  }
}

// ---------------------------------------------------------------------------
extern "C" void kernel_launch(void* const* d_in, const int* in_sizes, int n_in,
                              void* d_out, int out_size, void* d_ws,
                              size_t ws_size, hipStream_t stream) {
  const float* x    = (const float*)d_in[0];
  const int*   src  = (const int*)d_in[1];
  const int*   dst  = (const int*)d_in[2];
  const float* Wemb = (const float*)d_in[3];
  const float* bemb = (const float*)d_in[4];
  const float* W0   = (const float*)d_in[5];
  const float* al0  = (const float*)d_in[6];
  const float* ar0  = (const float*)d_in[7];
  const float* b0   = (const float*)d_in[8];
  const float* W1   = (const float*)d_in[9];
  const float* al1  = (const float*)d_in[10];
  const float* ar1  = (const float*)d_in[11];
  const float* b1   = (const float*)d_in[12];
  const float* W2   = (const float*)d_in[13];
  const float* al2  = (const float*)d_in[14];
  const float* ar2  = (const float*)d_in[15];
  const float* b2   = (const float*)d_in[16];
  const float* Wsc  = (const float*)d_in[17];
  const float* bsc  = (const float*)d_in[18];

  const int N = in_sizes[0] / 128;
  const int E = in_sizes[1];
  float* out = (float*)d_out;

  // workspace carve-up (16B-aligned buffers first)
  char* w = (char*)d_ws;
  float*  A    = (float*)w;  w += (size_t)N * 128 * 4;   // h ping
  float*  B    = (float*)w;  w += (size_t)N * 128 * 4;   // feat
  float2* edat = (float2*)w; w += (size_t)E * 2 * 8;     // per-head (ex, src)
  float* el  = (float*)w; w += (size_t)N * 2 * 4;
  float* er  = (float*)w; w += (size_t)N * 2 * 4;
  float* ps  = (float*)w; w += (size_t)N * 2 * 4;
  float* pd  = (float*)w; w += (size_t)N * 2 * 4;
  int* s_csr = (int*)w;   w += (size_t)E * 4;
  int* d_csr = (int*)w;   w += (size_t)E * 4;
  int* cnt   = (int*)w;   w += (size_t)N * 4;
  int* rp    = (int*)w;   w += (size_t)(N + 4) * 4;
  int* cur   = (int*)w;   w += (size_t)N * 4;

  // ---- CSR build (by dst) ----
  hipMemsetAsync(cnt, 0, (size_t)N * 4, stream);
  count_dst<<<(E + 255) / 256, 256, 0, stream>>>(dst, cnt, E);
  scan_all<<<1, 1024, 0, stream>>>(cnt, rp, cur, N);
  scatter_edges<<<(E + 255) / 256, 256, 0, stream>>>(src, dst, cur, s_csr,
                                                     d_csr, E);

  const int gb = (N + 63) / 64;
  const int eb = (E + 255) / 256;
  const int pb2 = (N * 2 + 15) / 16;   // pairs blocks, H=2 (16 pairs/block)
  const int pb1 = (N * 1 + 15) / 16;

  // ---- embedding ----
  gemm_k128<128><<<gb, 512, 0, stream>>>(x, Wemb, bemb, nullptr, nullptr,
                                         A, nullptr, nullptr, N);

  // ---- GAT layer 0 ----
  gemm_k128<128><<<gb, 512, 0, stream>>>(A, W0, nullptr, al0, ar0, B, el, er, N);
  edge_prep<2><<<eb, 256, 0, stream>>>(s_csr, d_csr, el, er, edat, E);
  gat_aggregate<2, false><<<pb2, 256, 0, stream>>>(B, edat, b0, rp, A,
                                                   nullptr, nullptr, nullptr,
                                                   N, E);
  // ---- GAT layer 1 ----
  gemm_k128<128><<<gb, 512, 0, stream>>>(A, W1, nullptr, al1, ar1, B, el, er, N);
  edge_prep<2><<<eb, 256, 0, stream>>>(s_csr, d_csr, el, er, edat, E);
  gat_aggregate<2, false><<<pb2, 256, 0, stream>>>(B, edat, b1, rp, A,
                                                   nullptr, nullptr, nullptr,
                                                   N, E);
  // ---- GAT layer 2 (1 head) + fused scorer partials ----
  gemm_k128<64><<<gb, 512, 0, stream>>>(A, W2, nullptr, al2, ar2, B, el, er, N);
  edge_prep<1><<<eb, 256, 0, stream>>>(s_csr, d_csr, el, er, edat, E);
  gat_aggregate<1, true><<<pb1, 256, 0, stream>>>(B, edat, b2, rp, A,
                                                  Wsc, ps, pd, N, E);

  // ---- edge scorer output ----
  score_out<<<(E + 255) / 256, 256, 0, stream>>>(src, dst, ps, pd, bsc, out, E);
}

// Round 5
// 516.568 us; speedup vs baseline: 1.2155x; 1.2155x over previous
//
#include <hip/hip_runtime.h>
#include <hip/hip_bf16.h>
#include <math.h>

// ---------------------------------------------------------------------------
// GAT edge classifier. Pipeline per call:
//   CSR build (memset, count, 3-kernel parallel scan, scatter)
//   emb GEMM -> 3x [ GEMM(+el/er epilogue) -> edge_prep -> aggregate ]
//   (last aggregate fuses the decomposed edge-scorer partials) -> score_out
// ---------------------------------------------------------------------------

constexpr float SLOPE = 0.2f;

// ---------- GEMM: Y = X[N,128] @ W[128,M] (+bias) [+ el/er epilogue] -------
template<int M>
__global__ __launch_bounds__(512)
void gemm_k128(const float* __restrict__ X, const float* __restrict__ W,
               const float* __restrict__ bias,
               const float* __restrict__ al, const float* __restrict__ ar,
               float* __restrict__ Y, float* __restrict__ el,
               float* __restrict__ er, int N) {
  constexpr int K = 128;
  constexpr int BM = 64;
  constexpr int CPT = M / 32;              // 4 (M=128) or 2 (M=64)
  constexpr int H = M / 64;
  __shared__ __align__(16) float Xs[BM][K];
  __shared__ __align__(16) float Wsm[K][M];

  const int tid = threadIdx.x;
  const int row0 = blockIdx.x * BM;

  #pragma unroll
  for (int j = 0; j < (BM * K) / (512 * 4); ++j) {
    int lin = tid + j * 512;
    int r = lin >> 5;
    int c4 = lin & 31;
    int gr = row0 + r;
    float4 v = make_float4(0.f, 0.f, 0.f, 0.f);
    if (gr < N) v = reinterpret_cast<const float4*>(X + (size_t)gr * K)[c4];
    reinterpret_cast<float4*>(&Xs[r][0])[c4] = v;
  }
  #pragma unroll
  for (int j = 0; j < (K * M) / (512 * 4); ++j) {
    int lin = tid + j * 512;
    reinterpret_cast<float4*>(&Wsm[0][0])[lin] =
        reinterpret_cast<const float4*>(W)[lin];
  }
  __syncthreads();

  const int tr = tid >> 5;                 // 16 row-groups of 4 rows
  const int tc = tid & 31;                 // 32 col-groups of CPT cols

  float acc[4][CPT];
  #pragma unroll
  for (int i = 0; i < 4; ++i)
    #pragma unroll
    for (int c = 0; c < CPT; ++c) acc[i][c] = 0.f;

  // k4-blocked: per 4 k-steps, 4 broadcast b128 (Xs) + 4 b128/b64 (Ws)
  #pragma unroll 2
  for (int k4 = 0; k4 < K / 4; ++k4) {
    float4 xv[4];
    #pragma unroll
    for (int i = 0; i < 4; ++i)
      xv[i] = *reinterpret_cast<const float4*>(&Xs[tr * 4 + i][k4 * 4]);
    if constexpr (CPT == 4) {
      float4 wv[4];
      #pragma unroll
      for (int kk = 0; kk < 4; ++kk)
        wv[kk] = *reinterpret_cast<const float4*>(&Wsm[k4 * 4 + kk][tc * 4]);
      #pragma unroll
      for (int i = 0; i < 4; ++i) {
        const float* xp = reinterpret_cast<const float*>(&xv[i]);
        #pragma unroll
        for (int kk = 0; kk < 4; ++kk) {
          acc[i][0] += xp[kk] * wv[kk].x;
          acc[i][1] += xp[kk] * wv[kk].y;
          acc[i][2] += xp[kk] * wv[kk].z;
          acc[i][3] += xp[kk] * wv[kk].w;
        }
      }
    } else {
      float2 wv[4];
      #pragma unroll
      for (int kk = 0; kk < 4; ++kk)
        wv[kk] = *reinterpret_cast<const float2*>(&Wsm[k4 * 4 + kk][tc * 2]);
      #pragma unroll
      for (int i = 0; i < 4; ++i) {
        const float* xp = reinterpret_cast<const float*>(&xv[i]);
        #pragma unroll
        for (int kk = 0; kk < 4; ++kk) {
          acc[i][0] += xp[kk] * wv[kk].x;
          acc[i][1] += xp[kk] * wv[kk].y;
        }
      }
    }
  }

  float bv[CPT];
  #pragma unroll
  for (int c = 0; c < CPT; ++c) bv[c] = bias ? bias[tc * CPT + c] : 0.f;

  #pragma unroll
  for (int i = 0; i < 4; ++i) {
    int gr = row0 + tr * 4 + i;
    if (gr < N) {
      if constexpr (CPT == 4) {
        float4 o = make_float4(acc[i][0] + bv[0], acc[i][1] + bv[1],
                               acc[i][2] + bv[2], acc[i][3] + bv[3]);
        *reinterpret_cast<float4*>(&Y[(size_t)gr * M + tc * 4]) = o;
      } else {
        float2 o = make_float2(acc[i][0] + bv[0], acc[i][1] + bv[1]);
        *reinterpret_cast<float2*>(&Y[(size_t)gr * M + tc * 2]) = o;
      }
    }
  }

  // ---- fused attention-coefficient epilogue: el/er = feat . al/ar ----
  if (al != nullptr) {
    int head, colbase;
    if constexpr (CPT == 4) { head = tc >> 4; colbase = tc * 4 - head * 64; }
    else                    { head = 0;       colbase = tc * 2; }
    float av[CPT], rv[CPT];
    #pragma unroll
    for (int c = 0; c < CPT; ++c) {
      av[c] = al[head * 64 + colbase + c];
      rv[c] = ar[head * 64 + colbase + c];
    }
    #pragma unroll
    for (int i = 0; i < 4; ++i) {
      float pl = 0.f, pr = 0.f;
      #pragma unroll
      for (int c = 0; c < CPT; ++c) {
        pl += acc[i][c] * av[c];
        pr += acc[i][c] * rv[c];
      }
      if constexpr (CPT == 4) {
        #pragma unroll
        for (int off = 1; off < 16; off <<= 1) {
          pl += __shfl_xor(pl, off);
          pr += __shfl_xor(pr, off);
        }
        if ((tc & 15) == 0) {
          int gr = row0 + tr * 4 + i;
          if (gr < N) { el[gr * H + head] = pl; er[gr * H + head] = pr; }
        }
      } else {
        #pragma unroll
        for (int off = 1; off < 32; off <<= 1) {
          pl += __shfl_xor(pl, off);
          pr += __shfl_xor(pr, off);
        }
        if (tc == 0) {
          int gr = row0 + tr * 4 + i;
          if (gr < N) { el[gr] = pl; er[gr] = pr; }
        }
      }
    }
  }
}

// ------------------------------ CSR build ----------------------------------
__global__ void count_dst(const int* __restrict__ dst, int* __restrict__ cnt,
                          int E) {
  int i = blockIdx.x * blockDim.x + threadIdx.x;
  if (i < E) atomicAdd(&cnt[dst[i]], 1);
}

// hierarchical scan: scan1 (per-1024-chunk), scan2 (block sums), scan3 (add)
__global__ void scan1(const int* __restrict__ cnt, int* __restrict__ outv,
                      int* __restrict__ bsum, int n) {
  __shared__ int sm[256];
  int tid = threadIdx.x;
  int base = blockIdx.x * 1024 + tid * 4;
  int pre[4];
  int s = 0;
  #pragma unroll
  for (int j = 0; j < 4; ++j) {
    int idx = base + j;
    int v = (idx < n) ? cnt[idx] : 0;
    pre[j] = s;
    s += v;
  }
  sm[tid] = s;
  __syncthreads();
  for (int off = 1; off < 256; off <<= 1) {
    int a = (tid >= off) ? sm[tid - off] : 0;
    __syncthreads();
    sm[tid] += a;
    __syncthreads();
  }
  int excl = sm[tid] - s;
  #pragma unroll
  for (int j = 0; j < 4; ++j) {
    int idx = base + j;
    if (idx < n) outv[idx] = excl + pre[j];
  }
  if (tid == 255) bsum[blockIdx.x] = sm[255];
}

__global__ void scan2(const int* __restrict__ bsum, int* __restrict__ btop,
                      int nb, int* __restrict__ row_last) {
  if (threadIdx.x == 0 && blockIdx.x == 0) {
    int s = 0;
    for (int i = 0; i < nb; ++i) { btop[i] = s; s += bsum[i]; }
    *row_last = s;
  }
}

__global__ void scan3(int* __restrict__ rp, int* __restrict__ cur,
                      const int* __restrict__ btop, int n) {
  int i = blockIdx.x * blockDim.x + threadIdx.x;
  if (i < n) {
    int v = rp[i] + btop[i >> 10];
    rp[i] = v;
    cur[i] = v;
  }
}

__global__ void scatter_edges(const int* __restrict__ src,
                              const int* __restrict__ dst,
                              int* __restrict__ cur,
                              int* __restrict__ s_csr,
                              int* __restrict__ d_csr, int E) {
  int i = blockIdx.x * blockDim.x + threadIdx.x;
  if (i < E) {
    int d = dst[i];
    int p = atomicAdd(&cur[d], 1);
    s_csr[p] = src[i];
    d_csr[p] = d;
  }
}

// ---- per-edge (CSR order) records: edat[h*E + p] = (exp(leaky), src) ------
template<int H>
__global__ void edge_prep(const int* __restrict__ s_csr,
                          const int* __restrict__ d_csr,
                          const float* __restrict__ el,
                          const float* __restrict__ er,
                          float2* __restrict__ edat, int E) {
  int i = blockIdx.x * blockDim.x + threadIdx.x;
  if (i >= E) return;
  int s = s_csr[i];
  int d = d_csr[i];
  float sb = __int_as_float(s);
  if constexpr (H == 2) {
    float2 le = reinterpret_cast<const float2*>(el)[s];
    float2 re = reinterpret_cast<const float2*>(er)[d];
    float e0 = le.x + re.x;
    float e1 = le.y + re.y;
    e0 = e0 > 0.f ? e0 : SLOPE * e0;
    e1 = e1 > 0.f ? e1 : SLOPE * e1;
    edat[i] = make_float2(__expf(e0), sb);
    edat[(size_t)E + i] = make_float2(__expf(e1), sb);
  } else {
    float ev = el[s] + er[d];
    ev = ev > 0.f ? ev : SLOPE * ev;
    edat[i] = make_float2(__expf(ev), sb);
  }
}

// ---------------- fused edge-softmax aggregation + bias + elu ---------------
// 16-lane group per (node,head): lane sl = float4 slot. No shuffles in the
// main path; each lane owns its final output float4. 8-edge unroll for MLP.
// SCORE: fuse the decomposed edge-scorer partials on the last layer.
template<int H, bool SCORE>
__global__ __launch_bounds__(256)
void gat_aggregate(const float* __restrict__ feat,
                   const float2* __restrict__ edat,
                   const float* __restrict__ bias,
                   const int* __restrict__ row_ptr,
                   float* __restrict__ hout,
                   const float* __restrict__ Wsc,
                   float* __restrict__ ps, float* __restrict__ pd,
                   int N, int E) {
  int tid = threadIdx.x;
  int pid = blockIdx.x * 16 + (tid >> 4);  // (node,head) pair id
  int sl = tid & 15;
  const int NH = N * H;
  bool live = pid < NH;
  int pc = live ? pid : 0;
  int node, head;
  if constexpr (H == 2) { node = pc >> 1; head = pc & 1; }
  else                  { node = pc;      head = 0; }
  int beg = live ? row_ptr[node] : 0;
  int end = live ? row_ptr[node + 1] : 0;

  const float4* feat4 = reinterpret_cast<const float4*>(feat);
  const int rowoff = head * 16 + sl;
  const float2* edath = edat + (size_t)head * E;

  float4 acc = make_float4(0.f, 0.f, 0.f, 0.f);
  float den = 0.f;

  for (int p = beg; p < end; p += 8) {
    #pragma unroll
    for (int j = 0; j < 8; ++j) {
      int q = p + j;
      int qc = q < end ? q : end - 1;
      float2 ed = edath[qc];
      float ex = q < end ? ed.x : 0.f;
      int s = __float_as_int(ed.y);
      float4 v = feat4[(size_t)s * (H * 16) + rowoff];
      den += ex;
      acc.x += ex * v.x;
      acc.y += ex * v.y;
      acc.z += ex * v.z;
      acc.w += ex * v.w;
    }
  }

  if (live) {
    float inv = 1.f / (den > 0.f ? den : 1.f);
    float4 bv = reinterpret_cast<const float4*>(bias)[head * 16 + sl];
    float4 r;
    r.x = acc.x * inv + bv.x;
    r.y = acc.y * inv + bv.y;
    r.z = acc.z * inv + bv.z;
    r.w = acc.w * inv + bv.w;
    r.x = r.x > 0.f ? r.x : expm1f(r.x);
    r.y = r.y > 0.f ? r.y : expm1f(r.y);
    r.z = r.z > 0.f ? r.z : expm1f(r.z);
    r.w = r.w > 0.f ? r.w : expm1f(r.w);
    reinterpret_cast<float4*>(hout)[(size_t)pid * 16 + sl] = r;

    if constexpr (SCORE) {
      // lane sl holds h3[node][4sl..4sl+3] in r; Wsc is [128][2] row-major
      float s0 = r.x * Wsc[(4 * sl + 0) * 2] + r.y * Wsc[(4 * sl + 1) * 2] +
                 r.z * Wsc[(4 * sl + 2) * 2] + r.w * Wsc[(4 * sl + 3) * 2];
      float s1 = r.x * Wsc[(4 * sl + 0) * 2 + 1] + r.y * Wsc[(4 * sl + 1) * 2 + 1] +
                 r.z * Wsc[(4 * sl + 2) * 2 + 1] + r.w * Wsc[(4 * sl + 3) * 2 + 1];
      float d0 = r.x * Wsc[(64 + 4 * sl + 0) * 2] + r.y * Wsc[(64 + 4 * sl + 1) * 2] +
                 r.z * Wsc[(64 + 4 * sl + 2) * 2] + r.w * Wsc[(64 + 4 * sl + 3) * 2];
      float d1 = r.x * Wsc[(64 + 4 * sl + 0) * 2 + 1] + r.y * Wsc[(64 + 4 * sl + 1) * 2 + 1] +
                 r.z * Wsc[(64 + 4 * sl + 2) * 2 + 1] + r.w * Wsc[(64 + 4 * sl + 3) * 2 + 1];
      #pragma unroll
      for (int off = 1; off < 16; off <<= 1) {   // stays inside 16-lane group
        s0 += __shfl_xor(s0, off);
        s1 += __shfl_xor(s1, off);
        d0 += __shfl_xor(d0, off);
        d1 += __shfl_xor(d1, off);
      }
      if (sl == 0) {
        ps[node * 2 + 0] = s0;
        ps[node * 2 + 1] = s1;
        pd[node * 2 + 0] = d0;
        pd[node * 2 + 1] = d1;
      }
    }
  }
}

// ----------------------- edge scorer output --------------------------------
__global__ void score_out(const int* __restrict__ src,
                          const int* __restrict__ dst,
                          const float* __restrict__ ps,
                          const float* __restrict__ pd,
                          const float* __restrict__ bs,
                          float* __restrict__ out, int E) {
  int i = blockIdx.x * blockDim.x + threadIdx.x;
  if (i < E) {
    int s = src[i], d = dst[i];
    float2 a = *reinterpret_cast<const float2*>(ps + (size_t)s * 2);
    float2 b = *reinterpret_cast<const float2*>(pd + (size_t)d * 2);
    float2 o;
    o.x = a.x + b.x + bs[0];
    o.y = a.y + b.y + bs[1];
    *reinterpret_cast<float2*>(out + (size_t)i * 2) = o;
  }
}

// ---------------------------------------------------------------------------
extern "C" void kernel_launch(void* const* d_in, const int* in_sizes, int n_in,
                              void* d_out, int out_size, void* d_ws,
                              size_t ws_size, hipStream_t stream) {
  const float* x    = (const float*)d_in[0];
  const int*   src  = (const int*)d_in[1];
  const int*   dst  = (const int*)d_in[2];
  const float* Wemb = (const float*)d_in[3];
  const float* bemb = (const float*)d_in[4];
  const float* W0   = (const float*)d_in[5];
  const float* al0  = (const float*)d_in[6];
  const float* ar0  = (const float*)d_in[7];
  const float* b0   = (const float*)d_in[8];
  const float* W1   = (const float*)d_in[9];
  const float* al1  = (const float*)d_in[10];
  const float* ar1  = (const float*)d_in[11];
  const float* b1   = (const float*)d_in[12];
  const float* W2   = (const float*)d_in[13];
  const float* al2  = (const float*)d_in[14];
  const float* ar2  = (const float*)d_in[15];
  const float* b2   = (const float*)d_in[16];
  const float* Wsc  = (const float*)d_in[17];
  const float* bsc  = (const float*)d_in[18];

  const int N = in_sizes[0] / 128;
  const int E = in_sizes[1];
  float* out = (float*)d_out;

  // workspace carve-up (16B-aligned buffers first)
  char* w = (char*)d_ws;
  float*  A    = (float*)w;  w += (size_t)N * 128 * 4;   // h ping
  float*  B    = (float*)w;  w += (size_t)N * 128 * 4;   // feat
  float2* edat = (float2*)w; w += (size_t)E * 2 * 8;     // per-head (ex, src)
  float* el  = (float*)w; w += (size_t)N * 2 * 4;
  float* er  = (float*)w; w += (size_t)N * 2 * 4;
  float* ps  = (float*)w; w += (size_t)N * 2 * 4;
  float* pd  = (float*)w; w += (size_t)N * 2 * 4;
  int* s_csr = (int*)w;   w += (size_t)E * 4;
  int* d_csr = (int*)w;   w += (size_t)E * 4;
  int* cnt   = (int*)w;   w += (size_t)N * 4;
  int* rp    = (int*)w;   w += (size_t)(N + 4) * 4;
  int* cur   = (int*)w;   w += (size_t)N * 4;
  int* bsum  = (int*)w;   w += 4096;
  int* btop  = (int*)w;   w += 4096;

  // ---- CSR build (by dst) ----
  hipMemsetAsync(cnt, 0, (size_t)N * 4, stream);
  count_dst<<<(E + 255) / 256, 256, 0, stream>>>(dst, cnt, E);
  int nb = (N + 1023) / 1024;
  scan1<<<nb, 256, 0, stream>>>(cnt, rp, bsum, N);
  scan2<<<1, 64, 0, stream>>>(bsum, btop, nb, rp + N);
  scan3<<<(N + 255) / 256, 256, 0, stream>>>(rp, cur, btop, N);
  scatter_edges<<<(E + 255) / 256, 256, 0, stream>>>(src, dst, cur, s_csr,
                                                     d_csr, E);

  const int gb = (N + 63) / 64;
  const int eb = (E + 255) / 256;
  const int pb2 = (N * 2 + 15) / 16;   // pairs blocks, H=2 (16 pairs/block)
  const int pb1 = (N * 1 + 15) / 16;

  // ---- embedding ----
  gemm_k128<128><<<gb, 512, 0, stream>>>(x, Wemb, bemb, nullptr, nullptr,
                                         A, nullptr, nullptr, N);

  // ---- GAT layer 0 ----
  gemm_k128<128><<<gb, 512, 0, stream>>>(A, W0, nullptr, al0, ar0, B, el, er, N);
  edge_prep<2><<<eb, 256, 0, stream>>>(s_csr, d_csr, el, er, edat, E);
  gat_aggregate<2, false><<<pb2, 256, 0, stream>>>(B, edat, b0, rp, A,
                                                   nullptr, nullptr, nullptr,
                                                   N, E);
  // ---- GAT layer 1 ----
  gemm_k128<128><<<gb, 512, 0, stream>>>(A, W1, nullptr, al1, ar1, B, el, er, N);
  edge_prep<2><<<eb, 256, 0, stream>>>(s_csr, d_csr, el, er, edat, E);
  gat_aggregate<2, false><<<pb2, 256, 0, stream>>>(B, edat, b1, rp, A,
                                                   nullptr, nullptr, nullptr,
                                                   N, E);
  // ---- GAT layer 2 (1 head) + fused scorer partials ----
  gemm_k128<64><<<gb, 512, 0, stream>>>(A, W2, nullptr, al2, ar2, B, el, er, N);
  edge_prep<1><<<eb, 256, 0, stream>>>(s_csr, d_csr, el, er, edat, E);
  gat_aggregate<1, true><<<pb1, 256, 0, stream>>>(B, edat, b2, rp, A,
                                                  Wsc, ps, pd, N, E);

  // ---- edge scorer output ----
  score_out<<<(E + 255) / 256, 256, 0, stream>>>(src, dst, ps, pd, bsc, out, E);
}

// Round 6
// 511.094 us; speedup vs baseline: 1.2285x; 1.0107x over previous
//
#include <hip/hip_runtime.h>
#include <hip/hip_bf16.h>
#include <math.h>

// ---------------------------------------------------------------------------
// GAT edge classifier. Pipeline per call:
//   CSR build (memset, count, 3-kernel parallel scan, scatter)
//   emb GEMM -> 3x [ GEMM(+el/er epilogue) -> fused aggregate(softmax inline) ]
//   (last aggregate fuses the decomposed edge-scorer partials) -> score_out
// ---------------------------------------------------------------------------

constexpr float SLOPE = 0.2f;

// ---------- GEMM: Y = X[N,128] @ W[128,M] (+bias) [+ el/er epilogue] -------
// W staged in two 64-row halves: LDS = 32KB(X) + 32/16KB(W) -> 2-3 blocks/CU.
template<int M>
__global__ __launch_bounds__(512)
void gemm_k128(const float* __restrict__ X, const float* __restrict__ W,
               const float* __restrict__ bias,
               const float* __restrict__ al, const float* __restrict__ ar,
               float* __restrict__ Y, float* __restrict__ el,
               float* __restrict__ er, int N) {
  constexpr int K = 128;
  constexpr int BM = 64;
  constexpr int CPT = M / 32;              // 4 (M=128) or 2 (M=64)
  constexpr int H = M / 64;
  constexpr int WH4 = (64 * M) / 4;        // float4s per W half
  __shared__ __align__(16) float Xs[BM][K];     // 32 KB
  __shared__ __align__(16) float Wsm[64][M];    // 32 KB (M=128) / 16 KB

  const int tid = threadIdx.x;
  const int row0 = blockIdx.x * BM;

  // stage X tile (full K)
  #pragma unroll
  for (int j = 0; j < (BM * K) / (512 * 4); ++j) {
    int lin = tid + j * 512;
    int r = lin >> 5;
    int c4 = lin & 31;
    int gr = row0 + r;
    float4 v = make_float4(0.f, 0.f, 0.f, 0.f);
    if (gr < N) v = reinterpret_cast<const float4*>(X + (size_t)gr * K)[c4];
    reinterpret_cast<float4*>(&Xs[r][0])[c4] = v;
  }
  // stage W half 0 (k rows 0..63)
  #pragma unroll
  for (int j = 0; j < WH4 / 512; ++j) {
    int lin = tid + j * 512;
    reinterpret_cast<float4*>(&Wsm[0][0])[lin] =
        reinterpret_cast<const float4*>(W)[lin];
  }
  __syncthreads();

  const int tr = tid >> 5;                 // 16 row-groups of 4 rows
  const int tc = tid & 31;                 // 32 col-groups of CPT cols

  float acc[4][CPT];
  #pragma unroll
  for (int i = 0; i < 4; ++i)
    #pragma unroll
    for (int c = 0; c < CPT; ++c) acc[i][c] = 0.f;

  #pragma unroll
  for (int half = 0; half < 2; ++half) {
    #pragma unroll 2
    for (int k4l = 0; k4l < 16; ++k4l) {
      const int kg = half * 64 + k4l * 4;  // global k base (Xs index)
      float4 xv[4];
      #pragma unroll
      for (int i = 0; i < 4; ++i)
        xv[i] = *reinterpret_cast<const float4*>(&Xs[tr * 4 + i][kg]);
      if constexpr (CPT == 4) {
        float4 wv[4];
        #pragma unroll
        for (int kk = 0; kk < 4; ++kk)
          wv[kk] = *reinterpret_cast<const float4*>(&Wsm[k4l * 4 + kk][tc * 4]);
        #pragma unroll
        for (int i = 0; i < 4; ++i) {
          const float* xp = reinterpret_cast<const float*>(&xv[i]);
          #pragma unroll
          for (int kk = 0; kk < 4; ++kk) {
            acc[i][0] += xp[kk] * wv[kk].x;
            acc[i][1] += xp[kk] * wv[kk].y;
            acc[i][2] += xp[kk] * wv[kk].z;
            acc[i][3] += xp[kk] * wv[kk].w;
          }
        }
      } else {
        float2 wv[4];
        #pragma unroll
        for (int kk = 0; kk < 4; ++kk)
          wv[kk] = *reinterpret_cast<const float2*>(&Wsm[k4l * 4 + kk][tc * 2]);
        #pragma unroll
        for (int i = 0; i < 4; ++i) {
          const float* xp = reinterpret_cast<const float*>(&xv[i]);
          #pragma unroll
          for (int kk = 0; kk < 4; ++kk) {
            acc[i][0] += xp[kk] * wv[kk].x;
            acc[i][1] += xp[kk] * wv[kk].y;
          }
        }
      }
    }
    if (half == 0) {
      __syncthreads();
      // stage W half 1 (k rows 64..127)
      #pragma unroll
      for (int j = 0; j < WH4 / 512; ++j) {
        int lin = tid + j * 512;
        reinterpret_cast<float4*>(&Wsm[0][0])[lin] =
            reinterpret_cast<const float4*>(W)[WH4 + lin];
      }
      __syncthreads();
    }
  }

  float bv[CPT];
  #pragma unroll
  for (int c = 0; c < CPT; ++c) bv[c] = bias ? bias[tc * CPT + c] : 0.f;

  #pragma unroll
  for (int i = 0; i < 4; ++i) {
    int gr = row0 + tr * 4 + i;
    if (gr < N) {
      if constexpr (CPT == 4) {
        float4 o = make_float4(acc[i][0] + bv[0], acc[i][1] + bv[1],
                               acc[i][2] + bv[2], acc[i][3] + bv[3]);
        *reinterpret_cast<float4*>(&Y[(size_t)gr * M + tc * 4]) = o;
      } else {
        float2 o = make_float2(acc[i][0] + bv[0], acc[i][1] + bv[1]);
        *reinterpret_cast<float2*>(&Y[(size_t)gr * M + tc * 2]) = o;
      }
    }
  }

  // ---- fused attention-coefficient epilogue: el/er = feat . al/ar ----
  if (al != nullptr) {
    int head, colbase;
    if constexpr (CPT == 4) { head = tc >> 4; colbase = tc * 4 - head * 64; }
    else                    { head = 0;       colbase = tc * 2; }
    float av[CPT], rv[CPT];
    #pragma unroll
    for (int c = 0; c < CPT; ++c) {
      av[c] = al[head * 64 + colbase + c];
      rv[c] = ar[head * 64 + colbase + c];
    }
    #pragma unroll
    for (int i = 0; i < 4; ++i) {
      float pl = 0.f, pr = 0.f;
      #pragma unroll
      for (int c = 0; c < CPT; ++c) {
        pl += acc[i][c] * av[c];
        pr += acc[i][c] * rv[c];
      }
      if constexpr (CPT == 4) {
        #pragma unroll
        for (int off = 1; off < 16; off <<= 1) {
          pl += __shfl_xor(pl, off);
          pr += __shfl_xor(pr, off);
        }
        if ((tc & 15) == 0) {
          int gr = row0 + tr * 4 + i;
          if (gr < N) { el[gr * H + head] = pl; er[gr * H + head] = pr; }
        }
      } else {
        #pragma unroll
        for (int off = 1; off < 32; off <<= 1) {
          pl += __shfl_xor(pl, off);
          pr += __shfl_xor(pr, off);
        }
        if (tc == 0) {
          int gr = row0 + tr * 4 + i;
          if (gr < N) { el[gr] = pl; er[gr] = pr; }
        }
      }
    }
  }
}

// ------------------------------ CSR build ----------------------------------
__global__ void count_dst(const int* __restrict__ dst, int* __restrict__ cnt,
                          int E) {
  int i = blockIdx.x * blockDim.x + threadIdx.x;
  if (i < E) atomicAdd(&cnt[dst[i]], 1);
}

// hierarchical scan: scan1 (per-1024-chunk), scan2 (block sums), scan3 (add)
__global__ void scan1(const int* __restrict__ cnt, int* __restrict__ outv,
                      int* __restrict__ bsum, int n) {
  __shared__ int sm[256];
  int tid = threadIdx.x;
  int base = blockIdx.x * 1024 + tid * 4;
  int pre[4];
  int s = 0;
  #pragma unroll
  for (int j = 0; j < 4; ++j) {
    int idx = base + j;
    int v = (idx < n) ? cnt[idx] : 0;
    pre[j] = s;
    s += v;
  }
  sm[tid] = s;
  __syncthreads();
  for (int off = 1; off < 256; off <<= 1) {
    int a = (tid >= off) ? sm[tid - off] : 0;
    __syncthreads();
    sm[tid] += a;
    __syncthreads();
  }
  int excl = sm[tid] - s;
  #pragma unroll
  for (int j = 0; j < 4; ++j) {
    int idx = base + j;
    if (idx < n) outv[idx] = excl + pre[j];
  }
  if (tid == 255) bsum[blockIdx.x] = sm[255];
}

__global__ void scan2(const int* __restrict__ bsum, int* __restrict__ btop,
                      int nb, int* __restrict__ row_last) {
  if (threadIdx.x == 0 && blockIdx.x == 0) {
    int s = 0;
    for (int i = 0; i < nb; ++i) { btop[i] = s; s += bsum[i]; }
    *row_last = s;
  }
}

__global__ void scan3(int* __restrict__ rp, int* __restrict__ cur,
                      const int* __restrict__ btop, int n) {
  int i = blockIdx.x * blockDim.x + threadIdx.x;
  if (i < n) {
    int v = rp[i] + btop[i >> 10];
    rp[i] = v;
    cur[i] = v;
  }
}

__global__ void scatter_edges(const int* __restrict__ src,
                              const int* __restrict__ dst,
                              int* __restrict__ cur,
                              int* __restrict__ s_csr, int E) {
  int i = blockIdx.x * blockDim.x + threadIdx.x;
  if (i < E) {
    int p = atomicAdd(&cur[dst[i]], 1);
    s_csr[p] = src[i];
  }
}

// -------- fused edge-softmax (inline exp) + aggregation + bias + elu -------
// 16-lane group per (node,head): lane sl = float4 slot. ex computed inline
// from el (L2-resident gather) + er (group-uniform). 8-edge unroll for MLP.
// SCORE: fuse the decomposed edge-scorer partials on the last layer.
template<int H, bool SCORE>
__global__ __launch_bounds__(256)
void gat_aggregate(const float* __restrict__ feat,
                   const int* __restrict__ s_csr,
                   const float* __restrict__ el,
                   const float* __restrict__ er,
                   const float* __restrict__ bias,
                   const int* __restrict__ row_ptr,
                   float* __restrict__ hout,
                   const float* __restrict__ Wsc,
                   float* __restrict__ ps, float* __restrict__ pd,
                   int N, int E) {
  int tid = threadIdx.x;
  int pid = blockIdx.x * 16 + (tid >> 4);  // (node,head) pair id
  int sl = tid & 15;
  const int NH = N * H;
  bool live = pid < NH;
  int pc = live ? pid : 0;
  int node, head;
  if constexpr (H == 2) { node = pc >> 1; head = pc & 1; }
  else                  { node = pc;      head = 0; }
  int beg = live ? row_ptr[node] : 0;
  int end = live ? row_ptr[node + 1] : 0;
  float ern = live ? er[pc] : 0.f;         // er[node*H+head]

  const float4* feat4 = reinterpret_cast<const float4*>(feat);
  const int rowoff = head * 16 + sl;

  float4 acc = make_float4(0.f, 0.f, 0.f, 0.f);
  float den = 0.f;

  for (int p = beg; p < end; p += 8) {
    #pragma unroll
    for (int j = 0; j < 8; ++j) {
      int q = p + j;
      int qc = q < end ? q : end - 1;
      int s = s_csr[qc];
      float ev = el[s * H + head] + ern;
      ev = ev > 0.f ? ev : SLOPE * ev;
      float ex = q < end ? __expf(ev) : 0.f;
      float4 v = feat4[(size_t)s * (H * 16) + rowoff];
      den += ex;
      acc.x += ex * v.x;
      acc.y += ex * v.y;
      acc.z += ex * v.z;
      acc.w += ex * v.w;
    }
  }

  if (live) {
    float inv = 1.f / (den > 0.f ? den : 1.f);
    float4 bv = reinterpret_cast<const float4*>(bias)[head * 16 + sl];
    float4 r;
    r.x = acc.x * inv + bv.x;
    r.y = acc.y * inv + bv.y;
    r.z = acc.z * inv + bv.z;
    r.w = acc.w * inv + bv.w;
    r.x = r.x > 0.f ? r.x : expm1f(r.x);
    r.y = r.y > 0.f ? r.y : expm1f(r.y);
    r.z = r.z > 0.f ? r.z : expm1f(r.z);
    r.w = r.w > 0.f ? r.w : expm1f(r.w);
    reinterpret_cast<float4*>(hout)[(size_t)pid * 16 + sl] = r;

    if constexpr (SCORE) {
      // lane sl holds h3[node][4sl..4sl+3] in r; Wsc is [128][2] row-major
      float s0 = r.x * Wsc[(4 * sl + 0) * 2] + r.y * Wsc[(4 * sl + 1) * 2] +
                 r.z * Wsc[(4 * sl + 2) * 2] + r.w * Wsc[(4 * sl + 3) * 2];
      float s1 = r.x * Wsc[(4 * sl + 0) * 2 + 1] + r.y * Wsc[(4 * sl + 1) * 2 + 1] +
                 r.z * Wsc[(4 * sl + 2) * 2 + 1] + r.w * Wsc[(4 * sl + 3) * 2 + 1];
      float d0 = r.x * Wsc[(64 + 4 * sl + 0) * 2] + r.y * Wsc[(64 + 4 * sl + 1) * 2] +
                 r.z * Wsc[(64 + 4 * sl + 2) * 2] + r.w * Wsc[(64 + 4 * sl + 3) * 2];
      float d1 = r.x * Wsc[(64 + 4 * sl + 0) * 2 + 1] + r.y * Wsc[(64 + 4 * sl + 1) * 2 + 1] +
                 r.z * Wsc[(64 + 4 * sl + 2) * 2 + 1] + r.w * Wsc[(64 + 4 * sl + 3) * 2 + 1];
      #pragma unroll
      for (int off = 1; off < 16; off <<= 1) {   // stays inside 16-lane group
        s0 += __shfl_xor(s0, off);
        s1 += __shfl_xor(s1, off);
        d0 += __shfl_xor(d0, off);
        d1 += __shfl_xor(d1, off);
      }
      if (sl == 0) {
        ps[node * 2 + 0] = s0;
        ps[node * 2 + 1] = s1;
        pd[node * 2 + 0] = d0;
        pd[node * 2 + 1] = d1;
      }
    }
  }
}

// ----------------------- edge scorer output --------------------------------
__global__ void score_out(const int* __restrict__ src,
                          const int* __restrict__ dst,
                          const float* __restrict__ ps,
                          const float* __restrict__ pd,
                          const float* __restrict__ bs,
                          float* __restrict__ out, int E) {
  int i = blockIdx.x * blockDim.x + threadIdx.x;
  if (i < E) {
    int s = src[i], d = dst[i];
    float2 a = *reinterpret_cast<const float2*>(ps + (size_t)s * 2);
    float2 b = *reinterpret_cast<const float2*>(pd + (size_t)d * 2);
    float2 o;
    o.x = a.x + b.x + bs[0];
    o.y = a.y + b.y + bs[1];
    *reinterpret_cast<float2*>(out + (size_t)i * 2) = o;
  }
}

// ---------------------------------------------------------------------------
extern "C" void kernel_launch(void* const* d_in, const int* in_sizes, int n_in,
                              void* d_out, int out_size, void* d_ws,
                              size_t ws_size, hipStream_t stream) {
  const float* x    = (const float*)d_in[0];
  const int*   src  = (const int*)d_in[1];
  const int*   dst  = (const int*)d_in[2];
  const float* Wemb = (const float*)d_in[3];
  const float* bemb = (const float*)d_in[4];
  const float* W0   = (const float*)d_in[5];
  const float* al0  = (const float*)d_in[6];
  const float* ar0  = (const float*)d_in[7];
  const float* b0   = (const float*)d_in[8];
  const float* W1   = (const float*)d_in[9];
  const float* al1  = (const float*)d_in[10];
  const float* ar1  = (const float*)d_in[11];
  const float* b1   = (const float*)d_in[12];
  const float* W2   = (const float*)d_in[13];
  const float* al2  = (const float*)d_in[14];
  const float* ar2  = (const float*)d_in[15];
  const float* b2   = (const float*)d_in[16];
  const float* Wsc  = (const float*)d_in[17];
  const float* bsc  = (const float*)d_in[18];

  const int N = in_sizes[0] / 128;
  const int E = in_sizes[1];
  float* out = (float*)d_out;

  // workspace carve-up (16B-aligned buffers first)
  char* w = (char*)d_ws;
  float* A   = (float*)w; w += (size_t)N * 128 * 4;   // h ping
  float* B   = (float*)w; w += (size_t)N * 128 * 4;   // feat
  float* el  = (float*)w; w += (size_t)N * 2 * 4;
  float* er  = (float*)w; w += (size_t)N * 2 * 4;
  float* ps  = (float*)w; w += (size_t)N * 2 * 4;
  float* pd  = (float*)w; w += (size_t)N * 2 * 4;
  int* s_csr = (int*)w;   w += (size_t)E * 4;
  int* cnt   = (int*)w;   w += (size_t)N * 4;
  int* rp    = (int*)w;   w += (size_t)(N + 4) * 4;
  int* cur   = (int*)w;   w += (size_t)N * 4;
  int* bsum  = (int*)w;   w += 4096;
  int* btop  = (int*)w;   w += 4096;

  // ---- CSR build (by dst) ----
  hipMemsetAsync(cnt, 0, (size_t)N * 4, stream);
  count_dst<<<(E + 255) / 256, 256, 0, stream>>>(dst, cnt, E);
  int nb = (N + 1023) / 1024;
  scan1<<<nb, 256, 0, stream>>>(cnt, rp, bsum, N);
  scan2<<<1, 64, 0, stream>>>(bsum, btop, nb, rp + N);
  scan3<<<(N + 255) / 256, 256, 0, stream>>>(rp, cur, btop, N);
  scatter_edges<<<(E + 255) / 256, 256, 0, stream>>>(src, dst, cur, s_csr, E);

  const int gb = (N + 63) / 64;
  const int pb2 = (N * 2 + 15) / 16;   // pair blocks, H=2 (16 groups/block)
  const int pb1 = (N * 1 + 15) / 16;

  // ---- embedding ----
  gemm_k128<128><<<gb, 512, 0, stream>>>(x, Wemb, bemb, nullptr, nullptr,
                                         A, nullptr, nullptr, N);

  // ---- GAT layer 0 ----
  gemm_k128<128><<<gb, 512, 0, stream>>>(A, W0, nullptr, al0, ar0, B, el, er, N);
  gat_aggregate<2, false><<<pb2, 256, 0, stream>>>(B, s_csr, el, er, b0, rp, A,
                                                   nullptr, nullptr, nullptr,
                                                   N, E);
  // ---- GAT layer 1 ----
  gemm_k128<128><<<gb, 512, 0, stream>>>(A, W1, nullptr, al1, ar1, B, el, er, N);
  gat_aggregate<2, false><<<pb2, 256, 0, stream>>>(B, s_csr, el, er, b1, rp, A,
                                                   nullptr, nullptr, nullptr,
                                                   N, E);
  // ---- GAT layer 2 (1 head) + fused scorer partials ----
  gemm_k128<64><<<gb, 512, 0, stream>>>(A, W2, nullptr, al2, ar2, B, el, er, N);
  gat_aggregate<1, true><<<pb1, 256, 0, stream>>>(B, s_csr, el, er, b2, rp, A,
                                                  Wsc, ps, pd, N, E);

  // ---- edge scorer output ----
  score_out<<<(E + 255) / 256, 256, 0, stream>>>(src, dst, ps, pd, bsc, out, E);
}

// Round 8
// 444.644 us; speedup vs baseline: 1.4121x; 1.1494x over previous
//
#include <hip/hip_runtime.h>
#include <hip/hip_bf16.h>
#include <math.h>

// ---------------------------------------------------------------------------
// GAT edge classifier. Pipeline per call:
//   CSR build (memset, count, 3-kernel scan, scatter)
//   emb GEMM(fp32 out) -> 3x [ GEMM(bf16 out + el/er epilogue) -> edge_prep
//     -> aggregate(bf16 gather, fp32 accum) ]
//   last aggregate emits decomposed edge-scorer partials -> score_out
// bf16 is used ONLY as the gather-source format (halves gather traffic);
// all arithmetic and all other tensors stay fp32.
// ---------------------------------------------------------------------------

constexpr float SLOPE = 0.2f;

__device__ __forceinline__ float b2f(unsigned short u) {
  union { unsigned int i; float f; } v;
  v.i = ((unsigned int)u) << 16;
  return v.f;
}
__device__ __forceinline__ unsigned short f2b(float f) {
  unsigned int x = __float_as_uint(f);
  unsigned int r = (x + 0x7fffu + ((x >> 16) & 1u)) >> 16;   // RNE
  return (unsigned short)r;
}

// ---------- GEMM: Y = X[N,128] @ W[128,M] (+bias) [+ el/er epilogue] -------
// W staged in two 64-row halves: LDS = 32KB(X) + 32/16KB(W) -> 2-3 blocks/CU.
// OUTBF16: store Y as bf16 (gather source); otherwise fp32.
template<int M, bool OUTBF16>
__global__ __launch_bounds__(512)
void gemm_k128(const float* __restrict__ X, const float* __restrict__ W,
               const float* __restrict__ bias,
               const float* __restrict__ al, const float* __restrict__ ar,
               void* __restrict__ Yv, float* __restrict__ el,
               float* __restrict__ er, int N) {
  constexpr int K = 128;
  constexpr int BM = 64;
  constexpr int CPT = M / 32;              // 4 (M=128) or 2 (M=64)
  constexpr int H = M / 64;
  constexpr int WH4 = (64 * M) / 4;        // float4s per W half
  __shared__ __align__(16) float Xs[BM][K];     // 32 KB
  __shared__ __align__(16) float Wsm[64][M];    // 32 KB (M=128) / 16 KB

  const int tid = threadIdx.x;
  const int row0 = blockIdx.x * BM;

  #pragma unroll
  for (int j = 0; j < (BM * K) / (512 * 4); ++j) {
    int lin = tid + j * 512;
    int r = lin >> 5;
    int c4 = lin & 31;
    int gr = row0 + r;
    float4 v = make_float4(0.f, 0.f, 0.f, 0.f);
    if (gr < N) v = reinterpret_cast<const float4*>(X + (size_t)gr * K)[c4];
    reinterpret_cast<float4*>(&Xs[r][0])[c4] = v;
  }
  #pragma unroll
  for (int j = 0; j < WH4 / 512; ++j) {
    int lin = tid + j * 512;
    reinterpret_cast<float4*>(&Wsm[0][0])[lin] =
        reinterpret_cast<const float4*>(W)[lin];
  }
  __syncthreads();

  const int tr = tid >> 5;                 // 16 row-groups of 4 rows
  const int tc = tid & 31;                 // 32 col-groups of CPT cols

  float acc[4][CPT];
  #pragma unroll
  for (int i = 0; i < 4; ++i)
    #pragma unroll
    for (int c = 0; c < CPT; ++c) acc[i][c] = 0.f;

  #pragma unroll
  for (int half = 0; half < 2; ++half) {
    #pragma unroll 2
    for (int k4l = 0; k4l < 16; ++k4l) {
      const int kg = half * 64 + k4l * 4;
      float4 xv[4];
      #pragma unroll
      for (int i = 0; i < 4; ++i)
        xv[i] = *reinterpret_cast<const float4*>(&Xs[tr * 4 + i][kg]);
      if constexpr (CPT == 4) {
        float4 wv[4];
        #pragma unroll
        for (int kk = 0; kk < 4; ++kk)
          wv[kk] = *reinterpret_cast<const float4*>(&Wsm[k4l * 4 + kk][tc * 4]);
        #pragma unroll
        for (int i = 0; i < 4; ++i) {
          const float* xp = reinterpret_cast<const float*>(&xv[i]);
          #pragma unroll
          for (int kk = 0; kk < 4; ++kk) {
            acc[i][0] += xp[kk] * wv[kk].x;
            acc[i][1] += xp[kk] * wv[kk].y;
            acc[i][2] += xp[kk] * wv[kk].z;
            acc[i][3] += xp[kk] * wv[kk].w;
          }
        }
      } else {
        float2 wv[4];
        #pragma unroll
        for (int kk = 0; kk < 4; ++kk)
          wv[kk] = *reinterpret_cast<const float2*>(&Wsm[k4l * 4 + kk][tc * 2]);
        #pragma unroll
        for (int i = 0; i < 4; ++i) {
          const float* xp = reinterpret_cast<const float*>(&xv[i]);
          #pragma unroll
          for (int kk = 0; kk < 4; ++kk) {
            acc[i][0] += xp[kk] * wv[kk].x;
            acc[i][1] += xp[kk] * wv[kk].y;
          }
        }
      }
    }
    if (half == 0) {
      __syncthreads();
      #pragma unroll
      for (int j = 0; j < WH4 / 512; ++j) {
        int lin = tid + j * 512;
        reinterpret_cast<float4*>(&Wsm[0][0])[lin] =
            reinterpret_cast<const float4*>(W)[WH4 + lin];
      }
      __syncthreads();
    }
  }

  float bv[CPT];
  #pragma unroll
  for (int c = 0; c < CPT; ++c) bv[c] = bias ? bias[tc * CPT + c] : 0.f;

  #pragma unroll
  for (int i = 0; i < 4; ++i) {
    int gr = row0 + tr * 4 + i;
    if (gr < N) {
      if constexpr (OUTBF16) {
        unsigned short* Yb = reinterpret_cast<unsigned short*>(Yv);
        if constexpr (CPT == 4) {
          ushort4 o;
          o.x = f2b(acc[i][0] + bv[0]);
          o.y = f2b(acc[i][1] + bv[1]);
          o.z = f2b(acc[i][2] + bv[2]);
          o.w = f2b(acc[i][3] + bv[3]);
          *reinterpret_cast<ushort4*>(&Yb[(size_t)gr * M + tc * 4]) = o;
        } else {
          ushort2 o;
          o.x = f2b(acc[i][0] + bv[0]);
          o.y = f2b(acc[i][1] + bv[1]);
          *reinterpret_cast<ushort2*>(&Yb[(size_t)gr * M + tc * 2]) = o;
        }
      } else {
        float* Y = reinterpret_cast<float*>(Yv);
        if constexpr (CPT == 4) {
          float4 o = make_float4(acc[i][0] + bv[0], acc[i][1] + bv[1],
                                 acc[i][2] + bv[2], acc[i][3] + bv[3]);
          *reinterpret_cast<float4*>(&Y[(size_t)gr * M + tc * 4]) = o;
        } else {
          float2 o = make_float2(acc[i][0] + bv[0], acc[i][1] + bv[1]);
          *reinterpret_cast<float2*>(&Y[(size_t)gr * M + tc * 2]) = o;
        }
      }
    }
  }

  // ---- fused attention-coefficient epilogue: el/er = feat . al/ar (fp32) ---
  if (al != nullptr) {
    int head, colbase;
    if constexpr (CPT == 4) { head = tc >> 4; colbase = tc * 4 - head * 64; }
    else                    { head = 0;       colbase = tc * 2; }
    float av[CPT], rv[CPT];
    #pragma unroll
    for (int c = 0; c < CPT; ++c) {
      av[c] = al[head * 64 + colbase + c];
      rv[c] = ar[head * 64 + colbase + c];
    }
    #pragma unroll
    for (int i = 0; i < 4; ++i) {
      float pl = 0.f, pr = 0.f;
      #pragma unroll
      for (int c = 0; c < CPT; ++c) {
        pl += acc[i][c] * av[c];
        pr += acc[i][c] * rv[c];
      }
      if constexpr (CPT == 4) {
        #pragma unroll
        for (int off = 1; off < 16; off <<= 1) {
          pl += __shfl_xor(pl, off);
          pr += __shfl_xor(pr, off);
        }
        if ((tc & 15) == 0) {
          int gr = row0 + tr * 4 + i;
          if (gr < N) { el[gr * H + head] = pl; er[gr * H + head] = pr; }
        }
      } else {
        #pragma unroll
        for (int off = 1; off < 32; off <<= 1) {
          pl += __shfl_xor(pl, off);
          pr += __shfl_xor(pr, off);
        }
        if (tc == 0) {
          int gr = row0 + tr * 4 + i;
          if (gr < N) { el[gr] = pl; er[gr] = pr; }
        }
      }
    }
  }
}

// ------------------------------ CSR build ----------------------------------
__global__ void count_dst(const int* __restrict__ dst, int* __restrict__ cnt,
                          int E) {
  int i = blockIdx.x * blockDim.x + threadIdx.x;
  if (i < E) atomicAdd(&cnt[dst[i]], 1);
}

__global__ void scan1(const int* __restrict__ cnt, int* __restrict__ outv,
                      int* __restrict__ bsum, int n) {
  __shared__ int sm[256];
  int tid = threadIdx.x;
  int base = blockIdx.x * 1024 + tid * 4;
  int pre[4];
  int s = 0;
  #pragma unroll
  for (int j = 0; j < 4; ++j) {
    int idx = base + j;
    int v = (idx < n) ? cnt[idx] : 0;
    pre[j] = s;
    s += v;
  }
  sm[tid] = s;
  __syncthreads();
  for (int off = 1; off < 256; off <<= 1) {
    int a = (tid >= off) ? sm[tid - off] : 0;
    __syncthreads();
    sm[tid] += a;
    __syncthreads();
  }
  int excl = sm[tid] - s;
  #pragma unroll
  for (int j = 0; j < 4; ++j) {
    int idx = base + j;
    if (idx < n) outv[idx] = excl + pre[j];
  }
  if (tid == 255) bsum[blockIdx.x] = sm[255];
}

__global__ void scan2(const int* __restrict__ bsum, int* __restrict__ btop,
                      int nb, int* __restrict__ row_last) {
  if (threadIdx.x == 0 && blockIdx.x == 0) {
    int s = 0;
    for (int i = 0; i < nb; ++i) { btop[i] = s; s += bsum[i]; }
    *row_last = s;
  }
}

__global__ void scan3(int* __restrict__ rp, int* __restrict__ cur,
                      const int* __restrict__ btop, int n) {
  int i = blockIdx.x * blockDim.x + threadIdx.x;
  if (i < n) {
    int v = rp[i] + btop[i >> 10];
    rp[i] = v;
    cur[i] = v;
  }
}

__global__ void scatter_edges(const int* __restrict__ src,
                              const int* __restrict__ dst,
                              int* __restrict__ cur,
                              int* __restrict__ s_csr,
                              int* __restrict__ d_csr, int E) {
  int i = blockIdx.x * blockDim.x + threadIdx.x;
  if (i < E) {
    int d = dst[i];
    int p = atomicAdd(&cur[d], 1);
    s_csr[p] = src[i];
    d_csr[p] = d;
  }
}

// ---- per-edge (CSR order) records: edat[h*E + p] = (exp(leaky), src) ------
template<int H>
__global__ void edge_prep(const int* __restrict__ s_csr,
                          const int* __restrict__ d_csr,
                          const float* __restrict__ el,
                          const float* __restrict__ er,
                          float2* __restrict__ edat, int E) {
  int i = blockIdx.x * blockDim.x + threadIdx.x;
  if (i >= E) return;
  int s = s_csr[i];
  int d = d_csr[i];
  float sb = __int_as_float(s);
  if constexpr (H == 2) {
    float2 le = reinterpret_cast<const float2*>(el)[s];
    float2 re = reinterpret_cast<const float2*>(er)[d];
    float e0 = le.x + re.x;
    float e1 = le.y + re.y;
    e0 = e0 > 0.f ? e0 : SLOPE * e0;
    e1 = e1 > 0.f ? e1 : SLOPE * e1;
    edat[i] = make_float2(__expf(e0), sb);
    edat[(size_t)E + i] = make_float2(__expf(e1), sb);
  } else {
    float ev = el[s] + er[d];
    ev = ev > 0.f ? ev : SLOPE * ev;
    edat[i] = make_float2(__expf(ev), sb);
  }
}

// ---------------- fused edge-softmax aggregation + bias + elu ---------------
// 16-lane group per (node,head); lane sl owns 4 output dims. Gathers feat in
// bf16 (8B/lane/edge), accumulates fp32. 8-edge unroll for MLP.
// SCORE: emit decomposed edge-scorer partials from registers; no hout write.
template<int H, bool SCORE>
__global__ __launch_bounds__(256)
void gat_aggregate(const unsigned short* __restrict__ featb,
                   const float2* __restrict__ edat,
                   const float* __restrict__ bias,
                   const int* __restrict__ row_ptr,
                   float* __restrict__ hout,
                   const float* __restrict__ Wsc,
                   float* __restrict__ ps, float* __restrict__ pd,
                   int N, int E) {
  int tid = threadIdx.x;
  int pid = blockIdx.x * 16 + (tid >> 4);  // (node,head) pair id
  int sl = tid & 15;
  const int NH = N * H;
  bool live = pid < NH;
  int pc = live ? pid : 0;
  int node, head;
  if constexpr (H == 2) { node = pc >> 1; head = pc & 1; }
  else                  { node = pc;      head = 0; }
  int beg = live ? row_ptr[node] : 0;
  int end = live ? row_ptr[node + 1] : 0;

  const int rowoff = head * 64 + sl * 4;   // bf16 elem offset within row
  const float2* edath = edat + (size_t)head * E;

  float4 acc = make_float4(0.f, 0.f, 0.f, 0.f);
  float den = 0.f;

  for (int p = beg; p < end; p += 8) {
    #pragma unroll
    for (int j = 0; j < 8; ++j) {
      int q = p + j;
      int qc = q < end ? q : end - 1;
      float2 ed = edath[qc];
      float ex = q < end ? ed.x : 0.f;
      int s = __float_as_int(ed.y);
      ushort4 u = *reinterpret_cast<const ushort4*>(
          &featb[(size_t)s * (H * 64) + rowoff]);
      den += ex;
      acc.x += ex * b2f(u.x);
      acc.y += ex * b2f(u.y);
      acc.z += ex * b2f(u.z);
      acc.w += ex * b2f(u.w);
    }
  }

  if (live) {
    float inv = 1.f / (den > 0.f ? den : 1.f);
    float4 bv = reinterpret_cast<const float4*>(bias)[head * 16 + sl];
    float4 r;
    r.x = acc.x * inv + bv.x;
    r.y = acc.y * inv + bv.y;
    r.z = acc.z * inv + bv.z;
    r.w = acc.w * inv + bv.w;
    r.x = r.x > 0.f ? r.x : expm1f(r.x);
    r.y = r.y > 0.f ? r.y : expm1f(r.y);
    r.z = r.z > 0.f ? r.z : expm1f(r.z);
    r.w = r.w > 0.f ? r.w : expm1f(r.w);

    if constexpr (!SCORE) {
      reinterpret_cast<float4*>(hout)[(size_t)pid * 16 + sl] = r;
    } else {
      // lane sl holds h3[node][4sl..4sl+3] in r; Wsc is [128][2] row-major
      float s0 = r.x * Wsc[(4 * sl + 0) * 2] + r.y * Wsc[(4 * sl + 1) * 2] +
                 r.z * Wsc[(4 * sl + 2) * 2] + r.w * Wsc[(4 * sl + 3) * 2];
      float s1 = r.x * Wsc[(4 * sl + 0) * 2 + 1] + r.y * Wsc[(4 * sl + 1) * 2 + 1] +
                 r.z * Wsc[(4 * sl + 2) * 2 + 1] + r.w * Wsc[(4 * sl + 3) * 2 + 1];
      float d0 = r.x * Wsc[(64 + 4 * sl + 0) * 2] + r.y * Wsc[(64 + 4 * sl + 1) * 2] +
                 r.z * Wsc[(64 + 4 * sl + 2) * 2] + r.w * Wsc[(64 + 4 * sl + 3) * 2];
      float d1 = r.x * Wsc[(64 + 4 * sl + 0) * 2 + 1] + r.y * Wsc[(64 + 4 * sl + 1) * 2 + 1] +
                 r.z * Wsc[(64 + 4 * sl + 2) * 2 + 1] + r.w * Wsc[(64 + 4 * sl + 3) * 2 + 1];
      #pragma unroll
      for (int off = 1; off < 16; off <<= 1) {   // stays inside 16-lane group
        s0 += __shfl_xor(s0, off);
        s1 += __shfl_xor(s1, off);
        d0 += __shfl_xor(d0, off);
        d1 += __shfl_xor(d1, off);
      }
      if (sl == 0) {
        ps[node * 2 + 0] = s0;
        ps[node * 2 + 1] = s1;
        pd[node * 2 + 0] = d0;
        pd[node * 2 + 1] = d1;
      }
    }
  }
}

// ----------------------- edge scorer output --------------------------------
__global__ void score_out(const int* __restrict__ src,
                          const int* __restrict__ dst,
                          const float* __restrict__ ps,
                          const float* __restrict__ pd,
                          const float* __restrict__ bs,
                          float* __restrict__ out, int E) {
  int i = blockIdx.x * blockDim.x + threadIdx.x;
  if (i < E) {
    int s = src[i], d = dst[i];
    float2 a = *reinterpret_cast<const float2*>(ps + (size_t)s * 2);
    float2 b = *reinterpret_cast<const float2*>(pd + (size_t)d * 2);
    float2 o;
    o.x = a.x + b.x + bs[0];
    o.y = a.y + b.y + bs[1];
    *reinterpret_cast<float2*>(out + (size_t)i * 2) = o;
  }
}

// ---------------------------------------------------------------------------
extern "C" void kernel_launch(void* const* d_in, const int* in_sizes, int n_in,
                              void* d_out, int out_size, void* d_ws,
                              size_t ws_size, hipStream_t stream) {
  const float* x    = (const float*)d_in[0];
  const int*   src  = (const int*)d_in[1];
  const int*   dst  = (const int*)d_in[2];
  const float* Wemb = (const float*)d_in[3];
  const float* bemb = (const float*)d_in[4];
  const float* W0   = (const float*)d_in[5];
  const float* al0  = (const float*)d_in[6];
  const float* ar0  = (const float*)d_in[7];
  const float* b0   = (const float*)d_in[8];
  const float* W1   = (const float*)d_in[9];
  const float* al1  = (const float*)d_in[10];
  const float* ar1  = (const float*)d_in[11];
  const float* b1   = (const float*)d_in[12];
  const float* W2   = (const float*)d_in[13];
  const float* al2  = (const float*)d_in[14];
  const float* ar2  = (const float*)d_in[15];
  const float* b2   = (const float*)d_in[16];
  const float* Wsc  = (const float*)d_in[17];
  const float* bsc  = (const float*)d_in[18];

  const int N = in_sizes[0] / 128;
  const int E = in_sizes[1];
  float* out = (float*)d_out;

  // workspace carve-up (16B-aligned buffers first)
  char* w = (char*)d_ws;
  float*  A    = (float*)w;  w += (size_t)N * 128 * 4;   // fp32 h (GEMM in/out)
  float2* edat = (float2*)w; w += (size_t)E * 2 * 8;     // per-head (ex, src)
  unsigned short* Bb = (unsigned short*)w; w += (size_t)N * 128 * 2; // bf16 feat
  float* el  = (float*)w; w += (size_t)N * 2 * 4;
  float* er  = (float*)w; w += (size_t)N * 2 * 4;
  float* ps  = (float*)w; w += (size_t)N * 2 * 4;
  float* pd  = (float*)w; w += (size_t)N * 2 * 4;
  int* s_csr = (int*)w;   w += (size_t)E * 4;
  int* d_csr = (int*)w;   w += (size_t)E * 4;
  int* cnt   = (int*)w;   w += (size_t)N * 4;
  int* rp    = (int*)w;   w += (size_t)(N + 4) * 4;
  int* cur   = (int*)w;   w += (size_t)N * 4;
  int* bsum  = (int*)w;   w += 4096;
  int* btop  = (int*)w;   w += 4096;

  // ---- CSR build (by dst) ----
  hipMemsetAsync(cnt, 0, (size_t)N * 4, stream);
  count_dst<<<(E + 255) / 256, 256, 0, stream>>>(dst, cnt, E);
  int nb = (N + 1023) / 1024;
  scan1<<<nb, 256, 0, stream>>>(cnt, rp, bsum, N);
  scan2<<<1, 64, 0, stream>>>(bsum, btop, nb, rp + N);
  scan3<<<(N + 255) / 256, 256, 0, stream>>>(rp, cur, btop, N);
  scatter_edges<<<(E + 255) / 256, 256, 0, stream>>>(src, dst, cur, s_csr,
                                                     d_csr, E);

  const int gb = (N + 63) / 64;
  const int eb = (E + 255) / 256;
  const int pb2 = (N * 2 + 15) / 16;   // pair blocks, H=2 (16 groups/block)
  const int pb1 = (N * 1 + 15) / 16;

  // ---- embedding (fp32 out) ----
  gemm_k128<128, false><<<gb, 512, 0, stream>>>(x, Wemb, bemb, nullptr, nullptr,
                                                A, nullptr, nullptr, N);

  // ---- GAT layer 0 ----
  gemm_k128<128, true><<<gb, 512, 0, stream>>>(A, W0, nullptr, al0, ar0,
                                               Bb, el, er, N);
  edge_prep<2><<<eb, 256, 0, stream>>>(s_csr, d_csr, el, er, edat, E);
  gat_aggregate<2, false><<<pb2, 256, 0, stream>>>(Bb, edat, b0, rp, A,
                                                   nullptr, nullptr, nullptr,
                                                   N, E);
  // ---- GAT layer 1 ----
  gemm_k128<128, true><<<gb, 512, 0, stream>>>(A, W1, nullptr, al1, ar1,
                                               Bb, el, er, N);
  edge_prep<2><<<eb, 256, 0, stream>>>(s_csr, d_csr, el, er, edat, E);
  gat_aggregate<2, false><<<pb2, 256, 0, stream>>>(Bb, edat, b1, rp, A,
                                                   nullptr, nullptr, nullptr,
                                                   N, E);
  // ---- GAT layer 2 (1 head) + fused scorer partials ----
  gemm_k128<64, true><<<gb, 512, 0, stream>>>(A, W2, nullptr, al2, ar2,
                                              Bb, el, er, N);
  edge_prep<1><<<eb, 256, 0, stream>>>(s_csr, d_csr, el, er, edat, E);
  gat_aggregate<1, true><<<pb1, 256, 0, stream>>>(Bb, edat, b2, rp, nullptr,
                                                  Wsc, ps, pd, N, E);

  // ---- edge scorer output ----
  score_out<<<(E + 255) / 256, 256, 0, stream>>>(src, dst, ps, pd, bsc, out, E);
}